// Round 5
// baseline (204129.260 us; speedup 1.0000x reference)
//
#include <hip/hip_runtime.h>
#include <stdint.h>

#define HID   512
#define SEQT  512
#define NB    32            // batches per group (= per XCD)
#define L1_RB 2064          // LDS row stride B, layer1: 2048 data + 16 pad
#define L0_RB 1072          // LDS row stride B, layer0: 1024 h0 + 16 u + 16 zeros + 16 pad
#define BUF1_U64 65536      // 256 rows * 256 u64 per h buffer
#define FPAD 16             // flags padded to 64B (16 ints)
#define POLL_CAP (1 << 21)  // ~0.3s escape hatch: converts deadlock into wrong-answer

typedef __attribute__((ext_vector_type(8)))  __bf16 bf16x8;
typedef __attribute__((ext_vector_type(16))) float  f32x16;
typedef unsigned long long u64;

__device__ __forceinline__ unsigned short f2bf(float x) {
  union { float f; unsigned u; } v; v.f = x;
  return (unsigned short)((v.u + 0x7FFFu + ((v.u >> 16) & 1u)) >> 16);  // RNE
}
__device__ __forceinline__ float bf2f(unsigned short h) {
  union { unsigned u; float f; } v; v.u = ((unsigned)h) << 16;
  return v.f;
}
__device__ __forceinline__ float sigm(float x)     { return 1.0f / (1.0f + __expf(-x)); }
__device__ __forceinline__ float tanhfast(float x) { return 2.0f / (1.0f + __expf(-2.0f * x)) - 1.0f; }

// XCD-local (intra-L2) communication: sc0 = bypass L1, coherent at the per-XCD L2.
// All producers/consumers of hbuf+flags live on the SAME XCD (groups formed from
// HW_REG_XCC_ID), so no sc1 / IF$ round-trip (R3's ~67% stall was IF$ RTTs).
__device__ __forceinline__ void st_l2(u64* p, u64 v) {
  asm volatile("global_store_dwordx2 %0, %1, off sc0" :: "v"(p), "v"(v) : "memory");
}
__device__ __forceinline__ u64 ld_l2(const u64* p) {
  u64 v;
  asm volatile("global_load_dwordx2 %0, %1, off sc0\n\ts_waitcnt vmcnt(0)"
               : "=v"(v) : "v"(p) : "memory");
  return v;
}
__device__ __forceinline__ void st_flag(int* p, int v) {
  asm volatile("global_store_dword %0, %1, off sc0" :: "v"(p), "v"(v) : "memory");
}
__device__ __forceinline__ int ld_flag(const int* p) {
  int v;
  asm volatile("global_load_dword %0, %1, off sc0\n\ts_waitcnt vmcnt(0)"
               : "=v"(v) : "v"(p) : "memory");
  return v;
}
// async global->LDS DMA, 16B/lane, cpol sc0 only (0x1): bypass L1, read per-XCD L2.
__device__ __forceinline__ void dma16(const void* g, void* l) {
  __builtin_amdgcn_global_load_lds((const unsigned int*)g, (unsigned int*)l, 16, 0, 0x1);
}

// 256 blocks, 1/CU (forced via 96KB LDS request) -> exactly 32 blocks per XCD.
// Group = physical XCD (HW_REG_XCC_ID, id 20); rank via atomicAdd on per-XCD counter.
// rank 0-15: layer0 block, 16-31: layer1 block; 32 batches per group.
__global__ __launch_bounds__(256, 1) void lstm_persist(
    const float* __restrict__ u_seq,
    const float* __restrict__ w_ih_0, const float* __restrict__ w_hh_0,
    const float* __restrict__ b_ih_0, const float* __restrict__ b_hh_0,
    const float* __restrict__ w_ih_1, const float* __restrict__ w_hh_1,
    const float* __restrict__ b_ih_1, const float* __restrict__ b_hh_1,
    const float* __restrict__ fc_w0, const float* __restrict__ fc_b0,
    const float* __restrict__ fc_w1, const float* __restrict__ fc_b1,
    float* __restrict__ out, int* flags, int* cnt, u64* hbuf)
{
  extern __shared__ char smemc[];    // B-tile staging (<=66KB used; 96KB requested)
  __shared__ int s_rank;

  const int tid  = threadIdx.x;
  // HW_REG_XCC_ID = hwreg id 20 (gfx940+); imm = (size-1)<<11 | offset<<6 | id
  int xcd = __builtin_amdgcn_s_getreg((31 << 11) | (0 << 6) | 20) & 7;
  if (tid == 0) s_rank = (atomicAdd(&cnt[xcd], 1) & 31);   // device-scope, once
  __syncthreads();
  const int rank = s_rank;
  const int g    = xcd;
  const int isL1 = rank >> 4;
  const int rl   = rank & 15;
  const int wv   = tid >> 6;
  const int lane = tid & 63;
  const int lcol = lane & 31;           // A row (gate row) / B col (batch)
  const int kh   = lane >> 5;           // K-half within MFMA step
  const int batch0 = g * NB;

  const int unit_base = rl * 32 + wv * 8;       // 8 units per wave
  const int prow = unit_base * 4 + lcol;        // permuted gate row (4u+gate)
  const int orig = (prow & 3) * HID + (prow >> 2);

  bool alive = true;   // latched false after a barrier timeout (invariant broke)
  auto groupbar = [&](int gen) {
    asm volatile("s_waitcnt vmcnt(0)" ::: "memory");  // h-stores L2-visible (asm ops
    __syncthreads();                                  // invisible to compiler's cnt)
    if (tid == 0) st_flag(&flags[(g * 32 + rank) * FPAD], gen);
    int timedout = 0;
    if (alive && tid < 32) {
      const int* fl = flags + (g * 32 + tid) * FPAD;
      int it = 0;
      while (ld_flag(fl) < gen) {
        __builtin_amdgcn_s_sleep(1);
        if (++it > POLL_CAP) { timedout = 1; break; }
      }
    }
    if (__any(timedout)) alive = false;
    __syncthreads();
  };

  // ---- zero OWN GROUP's h row (batch0+rank) in both buffers, sc0, in-bounds ----
  {
    u64* p = hbuf + (size_t)(batch0 + rank) * 256;    // 256 u64 = one 2KB row
    st_l2(p + tid, 0);
    st_l2(p + tid + BUF1_U64, 0);
  }
  int gen = 1;
  groupbar(gen++);

  if (isL1) {
    // ================= LAYER 1 BLOCK =================
    bf16x8 w[64];   // A-frags resident: 256 regs (1 wave/SIMD -> 512 budget)
    {
      const float* bih = w_ih_1 + (size_t)orig * HID;   // k<512: input = h0
      const float* bhh = w_hh_1 + (size_t)orig * HID;   // k>=512: recurrent h1
#pragma unroll
      for (int s = 0; s < 64; ++s) {
        int k = s * 16 + kh * 8;
        const float* src = (k < HID) ? (bih + k) : (bhh + (k - HID));
        float4 f0 = *(const float4*)src, f1 = *(const float4*)(src + 4);
        union { bf16x8 v; unsigned short h[8]; } u;
        u.h[0]=f2bf(f0.x); u.h[1]=f2bf(f0.y); u.h[2]=f2bf(f0.z); u.h[3]=f2bf(f0.w);
        u.h[4]=f2bf(f1.x); u.h[5]=f2bf(f1.y); u.h[6]=f2bf(f1.z); u.h[7]=f2bf(f1.w);
        w[s] = u.v;
      }
    }
    float bias[16];
#pragma unroll
    for (int rg = 0; rg < 16; ++rg) {
      int unit = unit_base + 2 * (rg >> 2) + kh;
      int gi = (rg & 3) * HID + unit;
      bias[rg] = b_ih_1[gi] + b_hh_1[gi];
    }
    float cc[4] = {0.f, 0.f, 0.f, 0.f};

    for (int tau = 0; tau <= SEQT; ++tau) {
      const char* curb = (const char*)(hbuf + ((tau & 1) ? BUF1_U64 : 0));
      u64*        nxt  = hbuf + ((tau & 1) ? 0 : BUF1_U64);
      if (tau >= 1) {
#pragma unroll
        for (int j = 0; j < 8; ++j) {
          int b = wv * 8 + j;
          const char* gr = curb + ((size_t)(batch0 + b) << 11) + lane * 16;
          char* lr = smemc + b * L1_RB;
          dma16(gr, lr);
          dma16(gr + 1024, lr + 1024);
        }
        __syncthreads();
        f32x16 a0, a1, a2, a3;
#pragma unroll
        for (int i = 0; i < 16; ++i) { a0[i] = bias[i]; a1[i] = 0.f; a2[i] = 0.f; a3[i] = 0.f; }
        const char* brow = smemc + lcol * L1_RB + kh * 16;
#pragma unroll
        for (int s = 0; s < 64; s += 4) {   // 4 indep chains -> ~8cy/MFMA issue floor
          bf16x8 b0 = *(const bf16x8*)(brow + s * 32);
          bf16x8 b1 = *(const bf16x8*)(brow + s * 32 + 32);
          bf16x8 b2 = *(const bf16x8*)(brow + s * 32 + 64);
          bf16x8 b3 = *(const bf16x8*)(brow + s * 32 + 96);
          a0 = __builtin_amdgcn_mfma_f32_32x32x16_bf16(w[s],     b0, a0, 0, 0, 0);
          a1 = __builtin_amdgcn_mfma_f32_32x32x16_bf16(w[s + 1], b1, a1, 0, 0, 0);
          a2 = __builtin_amdgcn_mfma_f32_32x32x16_bf16(w[s + 2], b2, a2, 0, 0, 0);
          a3 = __builtin_amdgcn_mfma_f32_32x32x16_bf16(w[s + 3], b3, a3, 0, 0, 0);
        }
        float hv[4];
#pragma unroll
        for (int q = 0; q < 4; ++q) {
          float ig = sigm(a0[4 * q + 0] + a1[4 * q + 0] + a2[4 * q + 0] + a3[4 * q + 0]);
          float fg = sigm(a0[4 * q + 1] + a1[4 * q + 1] + a2[4 * q + 1] + a3[4 * q + 1]);
          float gg = tanhfast(a0[4 * q + 2] + a1[4 * q + 2] + a2[4 * q + 2] + a3[4 * q + 2]);
          float og = sigm(a0[4 * q + 3] + a1[4 * q + 3] + a2[4 * q + 3] + a3[4 * q + 3]);
          float c = fg * cc[q] + ig * gg;
          cc[q] = c;
          hv[q] = og * tanhfast(c);
        }
        unsigned own01 = (unsigned)f2bf(hv[0]) | ((unsigned)f2bf(hv[1]) << 16);
        unsigned own23 = (unsigned)f2bf(hv[2]) | ((unsigned)f2bf(hv[3]) << 16);
        unsigned p01 = (unsigned)__shfl_xor((int)own01, 32);
        unsigned p23 = (unsigned)__shfl_xor((int)own23, 32);
        if (kh == 0) {   // interleave even(own)/odd(partner) units -> 16B contiguous
          u64 q0 = ((u64)((own01 & 0xffffu) | ((p01 & 0xffffu) << 16)))
                 | (((u64)((own01 >> 16) | (p01 & 0xffff0000u))) << 32);
          u64 q1 = ((u64)((own23 & 0xffffu) | ((p23 & 0xffffu) << 16)))
                 | (((u64)((own23 >> 16) | (p23 & 0xffff0000u))) << 32);
          u64* orow = nxt + (size_t)(batch0 + lcol) * 256 + 128 + (unit_base >> 2);
          st_l2(orow, q0);
          st_l2(orow + 1, q1);
        }
      }
      groupbar(gen++);
    }
  } else {
    // ================= LAYER 0 BLOCK =================
    bf16x8 w[33];
    {
      const float* bhh = w_hh_0 + (size_t)orig * HID;
#pragma unroll
      for (int s = 0; s < 32; ++s) {
        int k = s * 16 + kh * 8;
        float4 f0 = *(const float4*)(bhh + k), f1 = *(const float4*)(bhh + k + 4);
        union { bf16x8 v; unsigned short h[8]; } u;
        u.h[0]=f2bf(f0.x); u.h[1]=f2bf(f0.y); u.h[2]=f2bf(f0.z); u.h[3]=f2bf(f0.w);
        u.h[4]=f2bf(f1.x); u.h[5]=f2bf(f1.y); u.h[6]=f2bf(f1.z); u.h[7]=f2bf(f1.w);
        w[s] = u.v;
      }
      { // step 32: kh=0 -> u columns, kh=1 -> zeros (row pad region)
        union { bf16x8 v; unsigned short h[8]; } u;
        if (kh == 0) {
          const float* src = w_ih_0 + (size_t)orig * 8;
#pragma unroll
          for (int j = 0; j < 8; ++j) u.h[j] = f2bf(src[j]);
        } else {
#pragma unroll
          for (int j = 0; j < 8; ++j) u.h[j] = 0;
        }
        w[32] = u.v;
      }
    }
    float bias[16];
#pragma unroll
    for (int rg = 0; rg < 16; ++rg) {
      int unit = unit_base + 2 * (rg >> 2) + kh;
      int gi = (rg & 3) * HID + unit;
      bias[rg] = b_ih_0[gi] + b_hh_0[gi];
    }
    float cc[4] = {0.f, 0.f, 0.f, 0.f};

    // zeros for kh=1 of MFMA step 32: row bytes [1040,1056), written once
    if (tid < 64) *(u64*)(smemc + (tid >> 1) * L0_RB + 1040 + (tid & 1) * 8) = 0;

    for (int tau = 0; tau <= SEQT; ++tau) {
      const char* curb = (const char*)(hbuf + ((tau & 1) ? BUF1_U64 : 0));
      u64*        nxt  = hbuf + ((tau & 1) ? 0 : BUF1_U64);
      if (tau < SEQT) {
#pragma unroll
        for (int j = 0; j < 8; ++j) {
          int b = wv * 8 + j;
          const char* gr = curb + ((size_t)(batch0 + b) << 11) + lane * 16;
          dma16(gr, smemc + b * L0_RB);   // h0 half only (1KB)
        }
        { // stage u_tau into row bytes [1024,1040)
          int b = tid >> 3, i = tid & 7;
          ((unsigned short*)(smemc + b * L0_RB))[512 + i] =
              f2bf(u_seq[((size_t)(batch0 + b) * SEQT + tau) * 8 + i]);
        }
        __syncthreads();
        f32x16 a0, a1;
#pragma unroll
        for (int i = 0; i < 16; ++i) { a0[i] = bias[i]; a1[i] = 0.f; }
        const char* brow = smemc + lcol * L0_RB + kh * 16;
#pragma unroll
        for (int s = 0; s < 32; s += 2) {
          bf16x8 b0 = *(const bf16x8*)(brow + s * 32);
          bf16x8 b1 = *(const bf16x8*)(brow + s * 32 + 32);
          a0 = __builtin_amdgcn_mfma_f32_32x32x16_bf16(w[s],     b0, a0, 0, 0, 0);
          a1 = __builtin_amdgcn_mfma_f32_32x32x16_bf16(w[s + 1], b1, a1, 0, 0, 0);
        }
        { // step 32: u fold (kh=0) / zeros (kh=1)
          bf16x8 b2 = *(const bf16x8*)(brow + 32 * 32);
          a0 = __builtin_amdgcn_mfma_f32_32x32x16_bf16(w[32], b2, a0, 0, 0, 0);
        }
        float hv[4];
#pragma unroll
        for (int q = 0; q < 4; ++q) {
          float ig = sigm(a0[4 * q + 0] + a1[4 * q + 0]);
          float fg = sigm(a0[4 * q + 1] + a1[4 * q + 1]);
          float gg = tanhfast(a0[4 * q + 2] + a1[4 * q + 2]);
          float og = sigm(a0[4 * q + 3] + a1[4 * q + 3]);
          float c = fg * cc[q] + ig * gg;
          cc[q] = c;
          hv[q] = og * tanhfast(c);
        }
        unsigned own01 = (unsigned)f2bf(hv[0]) | ((unsigned)f2bf(hv[1]) << 16);
        unsigned own23 = (unsigned)f2bf(hv[2]) | ((unsigned)f2bf(hv[3]) << 16);
        unsigned p01 = (unsigned)__shfl_xor((int)own01, 32);
        unsigned p23 = (unsigned)__shfl_xor((int)own23, 32);
        if (kh == 0) {
          u64 q0 = ((u64)((own01 & 0xffffu) | ((p01 & 0xffffu) << 16)))
                 | (((u64)((own01 >> 16) | (p01 & 0xffff0000u))) << 32);
          u64 q1 = ((u64)((own23 & 0xffffu) | ((p23 & 0xffffu) << 16)))
                 | (((u64)((own23 >> 16) | (p23 & 0xffff0000u))) << 32);
          u64* orow = nxt + (size_t)(batch0 + lcol) * 256 + (unit_base >> 2);
          st_l2(orow, q0);
          st_l2(orow + 1, q1);
        }
      }
      groupbar(gen++);
    }
  }

  // ---- FC head (fp32): block (g,rank) handles batch g*32+rank (same-XCD data) ----
  {
    float* hT  = (float*)smemc;          // [512]
    float* hfc = ((float*)smemc) + 512;  // [256]
    const u64* hrow = hbuf + BUF1_U64 + (size_t)(batch0 + rank) * 256 + 128;  // h1_{T-1}
    if (tid < 128) {
      u64 v = ld_l2(hrow + tid);
      const unsigned short* s4 = (const unsigned short*)&v;
      hT[tid * 4 + 0] = bf2f(s4[0]);
      hT[tid * 4 + 1] = bf2f(s4[1]);
      hT[tid * 4 + 2] = bf2f(s4[2]);
      hT[tid * 4 + 3] = bf2f(s4[3]);
    }
    __syncthreads();
    {
      float s = fc_b0[tid];
      const float4* wrow = (const float4*)(fc_w0 + (size_t)tid * HID);
#pragma unroll 4
      for (int k4 = 0; k4 < 128; ++k4) {
        float4 wq = wrow[k4];
        s += hT[4 * k4 + 0] * wq.x + hT[4 * k4 + 1] * wq.y +
             hT[4 * k4 + 2] * wq.z + hT[4 * k4 + 3] * wq.w;
      }
      hfc[tid] = tanhfast(s);
    }
    __syncthreads();
    if (tid < 64) {
#pragma unroll
      for (int kk = 0; kk < 2; ++kk) {
        float p = 0.f;
        for (int j = tid; j < 256; j += 64) p += hfc[j] * fc_w1[kk * 256 + j];
#pragma unroll
        for (int off = 32; off; off >>= 1) p += __shfl_down(p, off, 64);
        if (tid == 0) out[(batch0 + rank) * 2 + kk] = p * 0.85f + (fc_b1[kk] * 0.85f + 3.35f);
      }
    }
  }
}

extern "C" void kernel_launch(void* const* d_in, const int* in_sizes, int n_in,
                              void* d_out, int out_size, void* d_ws, size_t ws_size,
                              hipStream_t stream) {
  const float* u_seq  = (const float*)d_in[0];
  const float* w_ih_0 = (const float*)d_in[1];
  const float* w_hh_0 = (const float*)d_in[2];
  const float* b_ih_0 = (const float*)d_in[3];
  const float* b_hh_0 = (const float*)d_in[4];
  const float* w_ih_1 = (const float*)d_in[5];
  const float* w_hh_1 = (const float*)d_in[6];
  const float* b_ih_1 = (const float*)d_in[7];
  const float* b_hh_1 = (const float*)d_in[8];
  const float* fc_w0  = (const float*)d_in[9];
  const float* fc_b0  = (const float*)d_in[10];
  const float* fc_w1  = (const float*)d_in[11];
  const float* fc_b1  = (const float*)d_in[12];
  float* out = (float*)d_out;

  // ws: [0,16KB) 64B-padded flags; [16KB,16KB+128B) per-XCD rank counters;
  //     [20KB, 20KB+1MB) double-buffered h (bf16, 2KB/row)
  int* flags = (int*)d_ws;
  int* cnt   = (int*)((char*)d_ws + 16384);
  u64* hbuf  = (u64*)((char*)d_ws + 20480);

  hipMemsetAsync(d_ws, 0, 20480, stream);   // flags + counters (graph-capturable)

  // Request 96KB dynamic LDS to FORCE 1 block/CU -> exactly 32 blocks per XCD,
  // which the XCC_ID-based grouping relies on.
  size_t shmem = 98304;
  hipFuncSetAttribute((const void*)lstm_persist,
                      hipFuncAttributeMaxDynamicSharedMemorySize, (int)shmem);
  hipLaunchKernelGGL(lstm_persist, dim3(256), dim3(256), shmem, stream,
                     u_seq, w_ih_0, w_hh_0, b_ih_0, b_hh_0,
                     w_ih_1, w_hh_1, b_ih_1, b_hh_1,
                     fc_w0, fc_b0, fc_w1, fc_b1, out, flags, cnt, hbuf);
}

// Round 6
// 4919.514 us; speedup vs baseline: 41.4938x; 41.4938x over previous
//
#include <hip/hip_runtime.h>
#include <stdint.h>

#define HID   512
#define SEQT  512
#define NB    32            // batches per group (= per XCD)
#define L1_RB 2064          // LDS row stride B, layer1: 2048 data + 16 pad
#define L0_RB 1072          // LDS row stride B, layer0: 1024 h0 + 16 u + 16 zeros + 16 pad
#define BUF1_U64 65536      // 256 rows * 256 u64 per h buffer
#define FPAD 16             // flags padded to 64B (16 ints)
#define POLL_CAP (1 << 18)  // ~75ms diagnostic escape hatch (signature, not a fix)

typedef __attribute__((ext_vector_type(8)))  __bf16 bf16x8;
typedef __attribute__((ext_vector_type(16))) float  f32x16;
typedef unsigned long long u64;

__device__ __forceinline__ unsigned short f2bf(float x) {
  union { float f; unsigned u; } v; v.f = x;
  return (unsigned short)((v.u + 0x7FFFu + ((v.u >> 16) & 1u)) >> 16);  // RNE
}
__device__ __forceinline__ float bf2f(unsigned short h) {
  union { unsigned u; float f; } v; v.u = ((unsigned)h) << 16;
  return v.f;
}
__device__ __forceinline__ float sigm(float x)     { return 1.0f / (1.0f + __expf(-x)); }
__device__ __forceinline__ float tanhfast(float x) { return 2.0f / (1.0f + __expf(-2.0f * x)) - 1.0f; }

// Bulk h-data: XCD-local via sc0 (reaches the shared per-XCD L2 through the
// write-through L1; producers+consumers share that L2 by construction).
__device__ __forceinline__ void st_l2(u64* p, u64 v) {
  asm volatile("global_store_dwordx2 %0, %1, off sc0" :: "v"(p), "v"(v) : "memory");
}
__device__ __forceinline__ u64 ld_l2(const u64* p) {
  u64 v;
  asm volatile("global_load_dwordx2 %0, %1, off sc0\n\ts_waitcnt vmcnt(0)"
               : "=v"(v) : "v"(p) : "memory");
  return v;
}
// async global->LDS DMA, 16B/lane, cpol sc0 (0x1): read via per-XCD L2.
__device__ __forceinline__ void dma16(const void* g, void* l) {
  __builtin_amdgcn_global_load_lds((const unsigned int*)g, (unsigned int*)l, 16, 0, 0x1);
}

// 256 blocks, 1/CU (forced via 96KB LDS request) -> exactly 32 blocks per XCD.
// Group = physical XCD (named hwreg, m09-verified); rank via device atomicAdd.
// rank 0-15: layer0 block, 16-31: layer1 block; 32 batches per group.
// FLAGS use agent-scope (sc1) atomics — R3-proven visibility path, independent
// of sc0 semantics. h-data uses sc0 + per-tick buffer_inv (L1 invalidate).
__global__ __launch_bounds__(256, 1) void lstm_persist(
    const float* __restrict__ u_seq,
    const float* __restrict__ w_ih_0, const float* __restrict__ w_hh_0,
    const float* __restrict__ b_ih_0, const float* __restrict__ b_hh_0,
    const float* __restrict__ w_ih_1, const float* __restrict__ w_hh_1,
    const float* __restrict__ b_ih_1, const float* __restrict__ b_hh_1,
    const float* __restrict__ fc_w0, const float* __restrict__ fc_b0,
    const float* __restrict__ fc_w1, const float* __restrict__ fc_b1,
    float* __restrict__ out, int* flags, int* cnt, u64* hbuf)
{
  extern __shared__ char smemc[];    // B-tile staging (<=66KB used; 96KB requested)
  __shared__ int s_rank;

  const int tid  = threadIdx.x;
  int xcd;
  asm volatile("s_getreg_b32 %0, hwreg(HW_REG_XCC_ID)" : "=s"(xcd));
  xcd &= 7;
  if (tid == 0) s_rank = (atomicAdd(&cnt[xcd], 1) & 31);   // device-scope, once
  __syncthreads();
  const int rank = s_rank;
  const int g    = xcd;
  const int isL1 = rank >> 4;
  const int rl   = rank & 15;
  const int wv   = tid >> 6;
  const int lane = tid & 63;
  const int lcol = lane & 31;           // A row (gate row) / B col (batch)
  const int kh   = lane >> 5;           // K-half within MFMA step
  const int batch0 = g * NB;

  const int unit_base = rl * 32 + wv * 8;       // 8 units per wave
  const int prow = unit_base * 4 + lcol;        // permuted gate row (4u+gate)
  const int orig = (prow & 3) * HID + (prow >> 2);

  bool alive = true;   // latched false after a barrier timeout (invariant broke)
  auto groupbar = [&](int gen) {
    asm volatile("s_waitcnt vmcnt(0)" ::: "memory");  // h-stores L2-visible
    __syncthreads();
    if (tid == 0)
      __hip_atomic_store(&flags[(g * 32 + rank) * FPAD], gen,
                         __ATOMIC_RELAXED, __HIP_MEMORY_SCOPE_AGENT);
    int timedout = 0;
    if (alive && tid < 32) {
      const int* fl = flags + (g * 32 + tid) * FPAD;
      int it = 0;
      while (__hip_atomic_load(fl, __ATOMIC_RELAXED, __HIP_MEMORY_SCOPE_AGENT) < gen) {
        if (++it > POLL_CAP) { timedout = 1; break; }
      }
    }
    if (__any(timedout)) alive = false;
    asm volatile("buffer_inv" ::: "memory");   // drop any stale L1 lines pre-staging
    __syncthreads();
  };

  // ---- zero OWN GROUP's h row (batch0+rank) in both buffers, sc0, in-bounds ----
  {
    u64* p = hbuf + (size_t)(batch0 + rank) * 256;    // 256 u64 = one 2KB row
    st_l2(p + tid, 0);
    st_l2(p + tid + BUF1_U64, 0);
  }
  int gen = 1;
  groupbar(gen++);

  if (isL1) {
    // ================= LAYER 1 BLOCK =================
    bf16x8 w[64];   // A-frags resident: 256 regs (1 wave/SIMD -> 512 unified budget)
    {
      const float* bih = w_ih_1 + (size_t)orig * HID;   // k<512: input = h0
      const float* bhh = w_hh_1 + (size_t)orig * HID;   // k>=512: recurrent h1
#pragma unroll
      for (int s = 0; s < 64; ++s) {
        int k = s * 16 + kh * 8;
        const float* src = (k < HID) ? (bih + k) : (bhh + (k - HID));
        float4 f0 = *(const float4*)src, f1 = *(const float4*)(src + 4);
        union { bf16x8 v; unsigned short h[8]; } u;
        u.h[0]=f2bf(f0.x); u.h[1]=f2bf(f0.y); u.h[2]=f2bf(f0.z); u.h[3]=f2bf(f0.w);
        u.h[4]=f2bf(f1.x); u.h[5]=f2bf(f1.y); u.h[6]=f2bf(f1.z); u.h[7]=f2bf(f1.w);
        w[s] = u.v;
      }
    }
    float bias[16];
#pragma unroll
    for (int rg = 0; rg < 16; ++rg) {
      int unit = unit_base + 2 * (rg >> 2) + kh;
      int gi = (rg & 3) * HID + unit;
      bias[rg] = b_ih_1[gi] + b_hh_1[gi];
    }
    float cc[4] = {0.f, 0.f, 0.f, 0.f};

    for (int tau = 0; tau <= SEQT; ++tau) {
      const char* curb = (const char*)(hbuf + ((tau & 1) ? BUF1_U64 : 0));
      u64*        nxt  = hbuf + ((tau & 1) ? 0 : BUF1_U64);
      if (tau >= 1) {
#pragma unroll
        for (int j = 0; j < 8; ++j) {
          int b = wv * 8 + j;
          const char* gr = curb + ((size_t)(batch0 + b) << 11) + lane * 16;
          char* lr = smemc + b * L1_RB;
          dma16(gr, lr);
          dma16(gr + 1024, lr + 1024);
        }
        __syncthreads();
        f32x16 a0, a1, a2, a3;
#pragma unroll
        for (int i = 0; i < 16; ++i) { a0[i] = bias[i]; a1[i] = 0.f; a2[i] = 0.f; a3[i] = 0.f; }
        const char* brow = smemc + lcol * L1_RB + kh * 16;
#pragma unroll
        for (int s = 0; s < 64; s += 4) {   // 4 indep chains -> ~8cy/MFMA issue floor
          bf16x8 b0 = *(const bf16x8*)(brow + s * 32);
          bf16x8 b1 = *(const bf16x8*)(brow + s * 32 + 32);
          bf16x8 b2 = *(const bf16x8*)(brow + s * 32 + 64);
          bf16x8 b3 = *(const bf16x8*)(brow + s * 32 + 96);
          a0 = __builtin_amdgcn_mfma_f32_32x32x16_bf16(w[s],     b0, a0, 0, 0, 0);
          a1 = __builtin_amdgcn_mfma_f32_32x32x16_bf16(w[s + 1], b1, a1, 0, 0, 0);
          a2 = __builtin_amdgcn_mfma_f32_32x32x16_bf16(w[s + 2], b2, a2, 0, 0, 0);
          a3 = __builtin_amdgcn_mfma_f32_32x32x16_bf16(w[s + 3], b3, a3, 0, 0, 0);
        }
        float hv[4];
#pragma unroll
        for (int q = 0; q < 4; ++q) {
          float ig = sigm(a0[4 * q + 0] + a1[4 * q + 0] + a2[4 * q + 0] + a3[4 * q + 0]);
          float fg = sigm(a0[4 * q + 1] + a1[4 * q + 1] + a2[4 * q + 1] + a3[4 * q + 1]);
          float gg = tanhfast(a0[4 * q + 2] + a1[4 * q + 2] + a2[4 * q + 2] + a3[4 * q + 2]);
          float og = sigm(a0[4 * q + 3] + a1[4 * q + 3] + a2[4 * q + 3] + a3[4 * q + 3]);
          float c = fg * cc[q] + ig * gg;
          cc[q] = c;
          hv[q] = og * tanhfast(c);
        }
        unsigned own01 = (unsigned)f2bf(hv[0]) | ((unsigned)f2bf(hv[1]) << 16);
        unsigned own23 = (unsigned)f2bf(hv[2]) | ((unsigned)f2bf(hv[3]) << 16);
        unsigned p01 = (unsigned)__shfl_xor((int)own01, 32);
        unsigned p23 = (unsigned)__shfl_xor((int)own23, 32);
        if (kh == 0) {   // interleave even(own)/odd(partner) units -> 16B contiguous
          u64 q0 = ((u64)((own01 & 0xffffu) | ((p01 & 0xffffu) << 16)))
                 | (((u64)((own01 >> 16) | (p01 & 0xffff0000u))) << 32);
          u64 q1 = ((u64)((own23 & 0xffffu) | ((p23 & 0xffffu) << 16)))
                 | (((u64)((own23 >> 16) | (p23 & 0xffff0000u))) << 32);
          u64* orow = nxt + (size_t)(batch0 + lcol) * 256 + 128 + (unit_base >> 2);
          st_l2(orow, q0);
          st_l2(orow + 1, q1);
        }
      }
      groupbar(gen++);
    }
  } else {
    // ================= LAYER 0 BLOCK =================
    bf16x8 w[33];
    {
      const float* bhh = w_hh_0 + (size_t)orig * HID;
#pragma unroll
      for (int s = 0; s < 32; ++s) {
        int k = s * 16 + kh * 8;
        float4 f0 = *(const float4*)(bhh + k), f1 = *(const float4*)(bhh + k + 4);
        union { bf16x8 v; unsigned short h[8]; } u;
        u.h[0]=f2bf(f0.x); u.h[1]=f2bf(f0.y); u.h[2]=f2bf(f0.z); u.h[3]=f2bf(f0.w);
        u.h[4]=f2bf(f1.x); u.h[5]=f2bf(f1.y); u.h[6]=f2bf(f1.z); u.h[7]=f2bf(f1.w);
        w[s] = u.v;
      }
      { // step 32: kh=0 -> u columns, kh=1 -> zeros (row pad region)
        union { bf16x8 v; unsigned short h[8]; } u;
        if (kh == 0) {
          const float* src = w_ih_0 + (size_t)orig * 8;
#pragma unroll
          for (int j = 0; j < 8; ++j) u.h[j] = f2bf(src[j]);
        } else {
#pragma unroll
          for (int j = 0; j < 8; ++j) u.h[j] = 0;
        }
        w[32] = u.v;
      }
    }
    float bias[16];
#pragma unroll
    for (int rg = 0; rg < 16; ++rg) {
      int unit = unit_base + 2 * (rg >> 2) + kh;
      int gi = (rg & 3) * HID + unit;
      bias[rg] = b_ih_0[gi] + b_hh_0[gi];
    }
    float cc[4] = {0.f, 0.f, 0.f, 0.f};

    // zeros for kh=1 of MFMA step 32: row bytes [1040,1056), written once
    if (tid < 64) *(u64*)(smemc + (tid >> 1) * L0_RB + 1040 + (tid & 1) * 8) = 0;

    const int ub = tid >> 3, ui = tid & 7;   // u staging: thread -> (batch, input)
    float upref = u_seq[((size_t)(batch0 + ub) * SEQT + 0) * 8 + ui];  // prefetch u_0

    for (int tau = 0; tau <= SEQT; ++tau) {
      const char* curb = (const char*)(hbuf + ((tau & 1) ? BUF1_U64 : 0));
      u64*        nxt  = hbuf + ((tau & 1) ? 0 : BUF1_U64);
      if (tau < SEQT) {
#pragma unroll
        for (int j = 0; j < 8; ++j) {
          int b = wv * 8 + j;
          const char* gr = curb + ((size_t)(batch0 + b) << 11) + lane * 16;
          dma16(gr, smemc + b * L0_RB);   // h0 half only (1KB)
        }
        // stage prefetched u_tau into row bytes [1024,1040)
        ((unsigned short*)(smemc + ub * L0_RB))[512 + ui] = f2bf(upref);
        __syncthreads();
        // prefetch u_{tau+1} now — off the next tick's critical path
        if (tau + 1 < SEQT)
          upref = u_seq[((size_t)(batch0 + ub) * SEQT + (tau + 1)) * 8 + ui];
        f32x16 a0, a1;
#pragma unroll
        for (int i = 0; i < 16; ++i) { a0[i] = bias[i]; a1[i] = 0.f; }
        const char* brow = smemc + lcol * L0_RB + kh * 16;
#pragma unroll
        for (int s = 0; s < 32; s += 2) {
          bf16x8 b0 = *(const bf16x8*)(brow + s * 32);
          bf16x8 b1 = *(const bf16x8*)(brow + s * 32 + 32);
          a0 = __builtin_amdgcn_mfma_f32_32x32x16_bf16(w[s],     b0, a0, 0, 0, 0);
          a1 = __builtin_amdgcn_mfma_f32_32x32x16_bf16(w[s + 1], b1, a1, 0, 0, 0);
        }
        { // step 32: u fold (kh=0) / zeros (kh=1)
          bf16x8 b2 = *(const bf16x8*)(brow + 32 * 32);
          a0 = __builtin_amdgcn_mfma_f32_32x32x16_bf16(w[32], b2, a0, 0, 0, 0);
        }
        float hv[4];
#pragma unroll
        for (int q = 0; q < 4; ++q) {
          float ig = sigm(a0[4 * q + 0] + a1[4 * q + 0]);
          float fg = sigm(a0[4 * q + 1] + a1[4 * q + 1]);
          float gg = tanhfast(a0[4 * q + 2] + a1[4 * q + 2]);
          float og = sigm(a0[4 * q + 3] + a1[4 * q + 3]);
          float c = fg * cc[q] + ig * gg;
          cc[q] = c;
          hv[q] = og * tanhfast(c);
        }
        unsigned own01 = (unsigned)f2bf(hv[0]) | ((unsigned)f2bf(hv[1]) << 16);
        unsigned own23 = (unsigned)f2bf(hv[2]) | ((unsigned)f2bf(hv[3]) << 16);
        unsigned p01 = (unsigned)__shfl_xor((int)own01, 32);
        unsigned p23 = (unsigned)__shfl_xor((int)own23, 32);
        if (kh == 0) {
          u64 q0 = ((u64)((own01 & 0xffffu) | ((p01 & 0xffffu) << 16)))
                 | (((u64)((own01 >> 16) | (p01 & 0xffff0000u))) << 32);
          u64 q1 = ((u64)((own23 & 0xffffu) | ((p23 & 0xffffu) << 16)))
                 | (((u64)((own23 >> 16) | (p23 & 0xffff0000u))) << 32);
          u64* orow = nxt + (size_t)(batch0 + lcol) * 256 + (unit_base >> 2);
          st_l2(orow, q0);
          st_l2(orow + 1, q1);
        }
      }
      groupbar(gen++);
    }
  }

  // ---- FC head (fp32): block (g,rank) handles batch g*32+rank (same-XCD data) ----
  {
    float* hT  = (float*)smemc;          // [512]
    float* hfc = ((float*)smemc) + 512;  // [256]
    const u64* hrow = hbuf + BUF1_U64 + (size_t)(batch0 + rank) * 256 + 128;  // h1_{T-1}
    if (tid < 128) {
      u64 v = ld_l2(hrow + tid);
      const unsigned short* s4 = (const unsigned short*)&v;
      hT[tid * 4 + 0] = bf2f(s4[0]);
      hT[tid * 4 + 1] = bf2f(s4[1]);
      hT[tid * 4 + 2] = bf2f(s4[2]);
      hT[tid * 4 + 3] = bf2f(s4[3]);
    }
    __syncthreads();
    {
      float s = fc_b0[tid];
      const float4* wrow = (const float4*)(fc_w0 + (size_t)tid * HID);
#pragma unroll 4
      for (int k4 = 0; k4 < 128; ++k4) {
        float4 wq = wrow[k4];
        s += hT[4 * k4 + 0] * wq.x + hT[4 * k4 + 1] * wq.y +
             hT[4 * k4 + 2] * wq.z + hT[4 * k4 + 3] * wq.w;
      }
      hfc[tid] = tanhfast(s);
    }
    __syncthreads();
    if (tid < 64) {
#pragma unroll
      for (int kk = 0; kk < 2; ++kk) {
        float p = 0.f;
        for (int j = tid; j < 256; j += 64) p += hfc[j] * fc_w1[kk * 256 + j];
#pragma unroll
        for (int off = 32; off; off >>= 1) p += __shfl_down(p, off, 64);
        if (tid == 0) out[(batch0 + rank) * 2 + kk] = p * 0.85f + (fc_b1[kk] * 0.85f + 3.35f);
      }
    }
  }
}

extern "C" void kernel_launch(void* const* d_in, const int* in_sizes, int n_in,
                              void* d_out, int out_size, void* d_ws, size_t ws_size,
                              hipStream_t stream) {
  const float* u_seq  = (const float*)d_in[0];
  const float* w_ih_0 = (const float*)d_in[1];
  const float* w_hh_0 = (const float*)d_in[2];
  const float* b_ih_0 = (const float*)d_in[3];
  const float* b_hh_0 = (const float*)d_in[4];
  const float* w_ih_1 = (const float*)d_in[5];
  const float* w_hh_1 = (const float*)d_in[6];
  const float* b_ih_1 = (const float*)d_in[7];
  const float* b_hh_1 = (const float*)d_in[8];
  const float* fc_w0  = (const float*)d_in[9];
  const float* fc_b0  = (const float*)d_in[10];
  const float* fc_w1  = (const float*)d_in[11];
  const float* fc_b1  = (const float*)d_in[12];
  float* out = (float*)d_out;

  // ws: [0,16KB) 64B-padded flags; [16KB,16KB+128B) per-XCD rank counters;
  //     [20KB, 20KB+1MB) double-buffered h (bf16, 2KB/row)
  int* flags = (int*)d_ws;
  int* cnt   = (int*)((char*)d_ws + 16384);
  u64* hbuf  = (u64*)((char*)d_ws + 20480);

  hipMemsetAsync(d_ws, 0, 20480, stream);   // flags + counters (graph-capturable)

  // Request 96KB dynamic LDS to FORCE 1 block/CU -> exactly 32 blocks per XCD,
  // which the XCC_ID-based grouping relies on.
  size_t shmem = 98304;
  hipFuncSetAttribute((const void*)lstm_persist,
                      hipFuncAttributeMaxDynamicSharedMemorySize, (int)shmem);
  hipLaunchKernelGGL(lstm_persist, dim3(256), dim3(256), shmem, stream,
                     u_seq, w_ih_0, w_hh_0, b_ih_0, b_hh_0,
                     w_ih_1, w_hh_1, b_ih_1, b_hh_1,
                     fc_w0, fc_b0, fc_w1, fc_b1, out, flags, cnt, hbuf);
}